// Round 2
// 294.714 us; speedup vs baseline: 1.0599x; 1.0599x over previous
//
#include <hip/hip_runtime.h>
#include <math.h>

// S5 SSM forward — R7 resubmit: 256² 8-phase MFMA GEMMs (m201 template:
// T2 st_16x32 LDS swizzle + T3/T4 counted-vmcnt 8-phase pipeline + T5 setprio).
// BSZ=4, L=4096, H=1024, P=512.
// prep(A1=[Bbar_re;Bbar_im] bf16, A2=[2Cr|-2Ci] bf16, Lambda_bar)
//   -> transpose u fp32[b][h][l] -> uT bf16 [b][l][h]
//   -> GEMM1 (8-phase MFMA): Bu fp32 [b][m][l], m = p (re) / 512+p (im)
//   -> scan (fp32 planar, in-place)   [replay-proven]
//   -> transpose xs fp32 -> xsT bf16 [b][l][m]   [replay-proven]
//   -> GEMM2 (8-phase MFMA) + D*u + exact GeLU -> out fp32 [b][h][l]

constexpr int kB = 4, kL = 4096, kH = 1024, kP = 512;
constexpr int kM = 1024, kK = 1024, kN = 4096;

typedef short bf16x8 __attribute__((ext_vector_type(8)));
typedef float f32x4 __attribute__((ext_vector_type(4)));

// ---- ws layout (bytes), MFMA path
constexpr size_t A1H_OFF = 0;                                    // 2 MiB
constexpr size_t A2H_OFF = A1H_OFF + (size_t)kM * kK * 2;        // 2 MiB
constexpr size_t LBAR_B  = A2H_OFF + (size_t)kM * kK * 2;        // 4 KiB
constexpr size_t BU_B    = (LBAR_B + 4096 + 255) & ~(size_t)255; // 64 MiB fp32
constexpr size_t TH_B    = BU_B + (size_t)kB * kM * kN * 4;      // 32 MiB bf16
constexpr size_t MID_BYTES = TH_B + (size_t)kB * kN * kK * 2;    // ~100 MiB

// ---- bf16 helpers
__device__ __forceinline__ unsigned short f2bf(float x) {
  unsigned int u = __float_as_uint(x);
  u += 0x7fffu + ((u >> 16) & 1u);
  return (unsigned short)(u >> 16);
}
__device__ __forceinline__ float bf2f(unsigned short h) {
  return __uint_as_float(((unsigned int)h) << 16);
}

__device__ __forceinline__ void gl2lds16(const void* g, void* l) {
  __builtin_amdgcn_global_load_lds(
      (const __attribute__((address_space(1))) void*)g,
      (__attribute__((address_space(3))) void*)l, 16, 0, 0);
}

// s_waitcnt with vmcnt=N, lgkmcnt/expcnt = don't-care
template <int N>
__device__ __forceinline__ void wait_vm() {
  __builtin_amdgcn_s_waitcnt((N & 15) | ((N >> 4) << 14) | (15 << 8) | (7 << 4));
}

// ---------------------------------------------------------------- prep1
__global__ __launch_bounds__(256) void k_prep1(
    const float* __restrict__ Lre, const float* __restrict__ Lim,
    const float* __restrict__ B, const float* __restrict__ log_step,
    unsigned char* __restrict__ ws) {
  int p = blockIdx.x;
  float lr = Lre[p], li = Lim[p];
  float step = expf(log_step[p]);
  float er = expf(lr * step);
  float sb, cb;
  sincosf(li * step, &sb, &cb);
  float lbr = er * cb, lbi = er * sb;
  float nr = lbr - 1.0f, ni = lbi;
  float inv = 1.0f / (lr * lr + li * li);
  float sr = (nr * lr + ni * li) * inv;
  float si = (ni * lr - nr * li) * inv;

  if (threadIdx.x == 0) ((float2*)(ws + LBAR_B))[p] = make_float2(lbr, lbi);

  unsigned short* a1h = (unsigned short*)(ws + A1H_OFF);
  const float* Brow = B + (size_t)p * kH * 2;
  for (int h = threadIdx.x; h < kH; h += 256) {
    float br = Brow[2 * h], bi = Brow[2 * h + 1];
    a1h[(size_t)p * kK + h] = f2bf(sr * br - si * bi);
    a1h[(size_t)(kP + p) * kK + h] = f2bf(sr * bi + si * br);
  }
}

// ---------------------------------------------------------------- prep2
// A2[h][k] = 2*Cr[h][k] (k<512) | -2*Ci[h][k-512]
__global__ __launch_bounds__(256) void k_prep2(
    const float* __restrict__ C, unsigned char* __restrict__ ws) {
  int h = blockIdx.x;
  unsigned short* a2h = (unsigned short*)(ws + A2H_OFF);
  for (int k = threadIdx.x; k < kK; k += 256) {
    float v = (k < kP) ? 2.f * C[((size_t)h * kP + k) * 2]
                       : -2.f * C[((size_t)h * kP + (k - kP)) * 2 + 1];
    a2h[(size_t)h * kK + k] = f2bf(v);
  }
}

// ---------------------------------------------------------------- transpose (fp32 -> bf16T)
// in: fp32 [b][1024][4096] -> out: bf16 [b][4096][1024]   [replay-proven]
__global__ __launch_bounds__(256) void k_transpose(
    const float* __restrict__ in, unsigned short* __restrict__ oh) {
  __shared__ float t[64][65];
  int b = blockIdx.z;
  int r0 = blockIdx.y * 64;
  int c0 = blockIdx.x * 64;
  int tid = threadIdx.x;
  const float* src = in + ((size_t)b * 1024 + r0) * 4096 + c0;
  int cc = (tid & 15) * 4, rr = tid >> 4;
#pragma unroll
  for (int i = 0; i < 4; i++) {
    float4 v = *(const float4*)(src + (size_t)(rr + i * 16) * 4096 + cc);
    t[rr + i * 16][cc + 0] = v.x;
    t[rr + i * 16][cc + 1] = v.y;
    t[rr + i * 16][cc + 2] = v.z;
    t[rr + i * 16][cc + 3] = v.w;
  }
  __syncthreads();
  int oc = tid >> 2;
  int og = (tid & 3) * 2;
#pragma unroll
  for (int i = 0; i < 2; i++) {
    int g = og + i;
    unsigned short hv[8];
#pragma unroll
    for (int j = 0; j < 8; j++) hv[j] = f2bf(t[g * 8 + j][oc]);
    size_t ob = ((size_t)b * 4096 + c0 + oc) * 1024 + r0 + g * 8;
    *(uint4*)(oh + ob) = *(uint4*)hv;
  }
}

// ================================================================ 8-phase GEMM
// 256x256 tile, BK=64, 512 threads = 8 waves (2M x 4N), per-wave out 128x64.
// LDS 128 KiB: A[2][256][64] + B[2][256][64] bf16, stored as 16x32 subtiles
// (1024 B each) with st_16x32 swizzle: byte ^= ((byte>>9)&1)<<5.
// Staging: global_load_lds writes LINEARLY (uniform base + lane*16); the
// swizzle is applied by inverse-permuting the per-lane GLOBAL source address
// (rule #21: linear dest + inv-swz source + swz read; same involution).

// For linear LDS byte Dp within a 16 KiB half-tile, return the element offset
// (row*kK + k) within the half-tile whose swizzled position is Dp.
__device__ __forceinline__ int stage_src_off(int Dp) {
  int Ds = Dp ^ (((Dp >> 9) & 1) << 5);  // involution
  int s = Ds >> 10, d = Ds & 1023;       // subtile, within-subtile byte
  int row = ((s >> 1) << 4) + (d >> 6);  // rb*16 + rl   (0..127)
  int kk = ((s & 1) << 5) + ((d & 63) >> 1);  // kb*32 + cl (mult of 8)
  return row * kK + kk;
}

// stage one 128-row half-tile (16 KiB): 2 x global_load_lds per thread
__device__ __forceinline__ void stg_half(const unsigned short* p, int h, int kt,
                                         unsigned char* lds, int lbase,
                                         int rowk0, int rowk1, int d0, int d1) {
  const unsigned short* s = p + (size_t)h * (128 * kK) + kt * 64;
  gl2lds16(s + rowk0, lds + lbase + h * 16384 + d0);
  gl2lds16(s + rowk1, lds + lbase + h * 16384 + d1);
}

// fragment reads: lane (q=lane>>4, r=lane&15) reads rows base+r, k=32*ks+8*q
template <int MH>
__device__ __forceinline__ void rd_ah(bf16x8 (&a)[4][2], const unsigned char* lds,
                                      int base, int wmrb, int lane_off) {
#pragma unroll
  for (int mi = 0; mi < 4; mi++)
#pragma unroll
    for (int ks = 0; ks < 2; ks++)
      a[mi][ks] = *(const bf16x8*)(lds + base +
          (((wmrb + MH * 4 + mi) * 2 + ks) << 10) + lane_off);
}
template <int NH>
__device__ __forceinline__ void rd_bh(bf16x8 (&bb)[2][2][2], const unsigned char* lds,
                                      int base, int wnrb, int lane_off) {
#pragma unroll
  for (int nj = 0; nj < 2; nj++)
#pragma unroll
    for (int ks = 0; ks < 2; ks++)
      bb[NH][nj][ks] = *(const bf16x8*)(lds + base +
          (((wnrb + NH * 2 + nj) * 2 + ks) << 10) + lane_off);
}

template <int MH, int NH>
__device__ __forceinline__ void mfma_quad(f32x4 (&acc)[8][4], bf16x8 (&a)[4][2],
                                          bf16x8 (&bb)[2][2][2]) {
  __builtin_amdgcn_s_setprio(1);
#pragma unroll
  for (int ks = 0; ks < 2; ks++)
#pragma unroll
    for (int mi = 0; mi < 4; mi++)
#pragma unroll
      for (int nj = 0; nj < 2; nj++)
        acc[MH * 4 + mi][NH * 2 + nj] = __builtin_amdgcn_mfma_f32_16x16x32_bf16(
            a[mi][ks], bb[NH][nj][ks], acc[MH * 4 + mi][NH * 2 + nj], 0, 0, 0);
  __builtin_amdgcn_s_setprio(0);
}

#define BAR __builtin_amdgcn_s_barrier()
#define LGKM0                                           \
  do {                                                  \
    asm volatile("s_waitcnt lgkmcnt(0)" ::: "memory");  \
    __builtin_amdgcn_sched_barrier(0);                  \
  } while (0)

template <bool EPI>
__global__ __launch_bounds__(512) void k_gemm8(
    const unsigned short* __restrict__ Ah, const unsigned short* __restrict__ Bh,
    float* __restrict__ out, const float* __restrict__ u,
    const float* __restrict__ D) {
  __shared__ __align__(16) unsigned char lds[131072];
  constexpr int LA0 = 0, LA1 = 32768, LB0 = 65536, LB1 = 98304;
  constexpr int NT2 = kK / 128;  // 8 iterations, 2 K-tiles each

  int b = blockIdx.z;
  int m0 = blockIdx.y * 256, n0 = blockIdx.x * 256;
  int tid = threadIdx.x, w = tid >> 6;
  int q = (tid >> 4) & 3, r = tid & 15;
  int wm = (w >> 2) * 128, wn = (w & 3) * 64;
  int wmrb = (w >> 2) * 8, wnrb = (w & 3) * 4;
  int lane_off = (r * 64 + q * 16) ^ ((r & 8) << 2);  // st_16x32 read swizzle

  int d0 = tid << 4, d1 = 8192 + (tid << 4);
  int rowk0 = stage_src_off(d0), rowk1 = stage_src_off(d1);

  const unsigned short* pA = Ah + (size_t)m0 * kK;
  const unsigned short* pB = Bh + (size_t)b * kN * kK + (size_t)n0 * kK;

  f32x4 acc[8][4] = {};
  bf16x8 a[4][2], bb[2][2][2];

#define STG(P, H, KT, LB) stg_half(P, H, KT, lds, LB, rowk0, rowk1, d0, d1)

  // prologue: buf0 <- kt0 full; buf1 <- kt1 B-halves (A-halves come in ph1/2)
  STG(pA, 0, 0, LA0); STG(pA, 1, 0, LA0);
  STG(pB, 0, 0, LB0); STG(pB, 1, 0, LB0);
  STG(pB, 0, 1, LB1); STG(pB, 1, 1, LB1);
  wait_vm<4>();  // buf0 landed; b1.B (4 loads) stays in flight
  BAR;

  for (int it = 0; it < NT2; ++it) {
    int kt = it * 2;
    bool pf = (it + 1 < NT2);
    // -------- phases 1-4: compute buf0 (K-tile kt)
    // ph1: quadrant (m0,n0); stage b1.A.h0 (kt+1)
    rd_ah<0>(a, lds, LA0, wmrb, lane_off);
    rd_bh<0>(bb, lds, LB0, wnrb, lane_off);
    STG(pA, 0, kt + 1, LA1);
    BAR; LGKM0; mfma_quad<0, 0>(acc, a, bb); BAR;
    // ph2: (m0,n1); stage b1.A.h1 (kt+1)
    rd_bh<1>(bb, lds, LB0, wnrb, lane_off);
    STG(pA, 1, kt + 1, LA1);
    BAR; LGKM0; mfma_quad<0, 1>(acc, a, bb); BAR;
    // ph3: (m1,n1); stage b0.B.h0 (kt+2)  [B last read ph2]
    rd_ah<1>(a, lds, LA0, wmrb, lane_off);
    if (pf) STG(pB, 0, kt + 2, LB0);
    BAR; LGKM0; mfma_quad<1, 1>(acc, a, bb); BAR;
    // ph4: (m1,n0) reuses regs; stage b0.B.h1; GATE for buf1
    if (pf) STG(pB, 1, kt + 2, LB0);
    BAR; mfma_quad<1, 0>(acc, a, bb);
    if (pf) wait_vm<4>(); else wait_vm<0>();  // b1 stages (prev ph7/8 + ph1/2) landed
    BAR;
    // -------- phases 5-8: compute buf1 (K-tile kt+1)
    // ph5: (m0,n0); stage b0.A.h0 (kt+2)  [A last read ph3]
    rd_ah<0>(a, lds, LA1, wmrb, lane_off);
    rd_bh<0>(bb, lds, LB1, wnrb, lane_off);
    if (pf) STG(pA, 0, kt + 2, LA0);
    BAR; LGKM0; mfma_quad<0, 0>(acc, a, bb); BAR;
    // ph6: (m0,n1); stage b0.A.h1 (kt+2)
    rd_bh<1>(bb, lds, LB1, wnrb, lane_off);
    if (pf) STG(pA, 1, kt + 2, LA0);
    BAR; LGKM0; mfma_quad<0, 1>(acc, a, bb); BAR;
    // ph7: (m1,n1); stage b1.B.h0 (kt+3)  [b1.B last read ph6]
    rd_ah<1>(a, lds, LA1, wmrb, lane_off);
    if (pf) STG(pB, 0, kt + 3, LB1);
    BAR; LGKM0; mfma_quad<1, 1>(acc, a, bb); BAR;
    // ph8: (m1,n0); stage b1.B.h1 (kt+3); GATE for buf0 of next iter
    if (pf) STG(pB, 1, kt + 3, LB1);
    BAR; mfma_quad<1, 0>(acc, a, bb);
    if (pf) wait_vm<4>();  // b0 stages (ph3-6) landed before next-iter ph1
    BAR;
  }
#undef STG

  // C/D layout: col = r, row = q*4 + reg
#pragma unroll
  for (int mi = 0; mi < 8; mi++) {
#pragma unroll
    for (int reg = 0; reg < 4; reg++) {
      int row = m0 + wm + mi * 16 + q * 4 + reg;
      float dv = EPI ? D[row] : 0.f;
#pragma unroll
      for (int ni = 0; ni < 4; ni++) {
        int col = n0 + wn + ni * 16 + r;
        size_t o = ((size_t)b * kM + row) * (size_t)kN + col;
        float v = acc[mi][ni][reg];
        if (EPI) {
          float y = v + dv * u[o];
          v = 0.5f * y * (1.f + erff(y * 0.70710678118654752f));
        }
        out[o] = v;
      }
    }
  }
}

// ---------------------------------------------------------------- scan (fp32 planar, in-place)
// [replay-proven]
__global__ __launch_bounds__(256) void k_scan(float* __restrict__ bu,
                                              const float2* __restrict__ lbar) {
  int p = blockIdx.x & (kP - 1);
  int b = blockIdx.x >> 9;
  int tid = threadIdx.x, lane = tid & 63, w = tid >> 6;
  float2 lam = lbar[p];
  float* sre = bu + ((size_t)b * kM + p) * (size_t)kN;
  float* sim = sre + (size_t)kP * kN;

  float vr[16], vi[16];
  {
    const float4* pr = (const float4*)(sre + tid * 16);
    const float4* pi = (const float4*)(sim + tid * 16);
#pragma unroll
    for (int i = 0; i < 4; i++) {
      float4 a = pr[i], c = pi[i];
      vr[4 * i] = a.x; vr[4 * i + 1] = a.y; vr[4 * i + 2] = a.z; vr[4 * i + 3] = a.w;
      vi[4 * i] = c.x; vi[4 * i + 1] = c.y; vi[4 * i + 2] = c.z; vi[4 * i + 3] = c.w;
    }
  }

  float xr = 0.f, xi = 0.f;
#pragma unroll
  for (int i = 0; i < 16; i++) {
    float nr2 = fmaf(lam.x, xr, fmaf(-lam.y, xi, vr[i]));
    float ni2 = fmaf(lam.x, xi, fmaf(lam.y, xr, vi[i]));
    xr = nr2; xi = ni2;
  }

  float Ar = lam.x, Ai = lam.y;
#pragma unroll
  for (int s = 0; s < 4; s++) {
    float tr = Ar * Ar - Ai * Ai, ti = 2.f * Ar * Ai;
    Ar = tr; Ai = ti;
  }
  float br = xr, bi = xi;

  for (int off = 1; off < 64; off <<= 1) {
    float pAr = __shfl_up(Ar, off), pAi = __shfl_up(Ai, off);
    float pbr = __shfl_up(br, off), pbi = __shfl_up(bi, off);
    if (lane >= off) {
      float nAr = Ar * pAr - Ai * pAi;
      float nAi = Ar * pAi + Ai * pAr;
      float nbr = Ar * pbr - Ai * pbi + br;
      float nbi = Ar * pbi + Ai * pbr + bi;
      Ar = nAr; Ai = nAi; br = nbr; bi = nbi;
    }
  }

  __shared__ float4 wtot[4];
  if (lane == 63) wtot[w] = make_float4(Ar, Ai, br, bi);
  __syncthreads();

  float eAr = __shfl_up(Ar, 1), eAi = __shfl_up(Ai, 1);
  float ebr = __shfl_up(br, 1), ebi = __shfl_up(bi, 1);
  if (lane == 0) { eAr = 1.f; eAi = 0.f; ebr = 0.f; ebi = 0.f; }

  float pAr = 1.f, pAi = 0.f, pbr = 0.f, pbi = 0.f;
  for (int j = 0; j < w; j++) {
    float4 t = wtot[j];
    float nAr = t.x * pAr - t.y * pAi;
    float nAi = t.x * pAi + t.y * pAr;
    float nbr = t.x * pbr - t.y * pbi + t.z;
    float nbi = t.x * pbi + t.y * pbr + t.w;
    pAr = nAr; pAi = nAi; pbr = nbr; pbi = nbi;
  }

  float initr = eAr * pbr - eAi * pbi + ebr;
  float initi = eAr * pbi + eAi * pbr + ebi;

  xr = initr; xi = initi;
  float4* qr = (float4*)(sre + tid * 16);
  float4* qi = (float4*)(sim + tid * 16);
#pragma unroll
  for (int i = 0; i < 4; i++) {
    float rr[4], ii[4];
#pragma unroll
    for (int j = 0; j < 4; j++) {
      float nr2 = fmaf(lam.x, xr, fmaf(-lam.y, xi, vr[4 * i + j]));
      float ni2 = fmaf(lam.x, xi, fmaf(lam.y, xr, vi[4 * i + j]));
      xr = nr2; xi = ni2; rr[j] = nr2; ii[j] = ni2;
    }
    qr[i] = make_float4(rr[0], rr[1], rr[2], rr[3]);
    qi[i] = make_float4(ii[0], ii[1], ii[2], ii[3]);
  }
}

// ================================================================ fp32 fallback
constexpr size_t OBBAR = 0;
constexpr size_t OLBAR = (size_t)kP * kH;
constexpr size_t OBU = OLBAR + 1024;

__global__ __launch_bounds__(256) void k_precomputeF(
    const float* __restrict__ Lre, const float* __restrict__ Lim,
    const float* __restrict__ B, const float* __restrict__ log_step,
    float2* __restrict__ ws) {
  int p = blockIdx.x;
  float lr = Lre[p], li = Lim[p];
  float step = expf(log_step[p]);
  float er = expf(lr * step);
  float sb, cb;
  sincosf(li * step, &sb, &cb);
  float lbr = er * cb, lbi = er * sb;
  float nr = lbr - 1.0f, ni = lbi;
  float inv = 1.0f / (lr * lr + li * li);
  float sr = (nr * lr + ni * li) * inv;
  float si = (ni * lr - nr * li) * inv;
  if (threadIdx.x == 0) ws[OLBAR + p] = make_float2(lbr, lbi);
  float2* Bbar = ws + OBBAR;
  const float* Brow = B + (size_t)p * kH * 2;
  for (int h = threadIdx.x; h < kH; h += 256) {
    float br = Brow[2 * h], bi = Brow[2 * h + 1];
    Bbar[(size_t)p * kH + h] = make_float2(sr * br - si * bi, sr * bi + si * br);
  }
}

__global__ __launch_bounds__(256) void k_gemm1F(
    const float2* __restrict__ ws_bbar, const float* __restrict__ u,
    float2* __restrict__ Bu) {
  __shared__ float2 As[16][64];
  __shared__ float Bs[16][64];
  int b = blockIdx.z, m0 = blockIdx.y * 64, n0 = blockIdx.x * 64;
  int tid = threadIdx.x, tn = tid & 15, tm = tid >> 4;
  const float* uB = u + (size_t)b * kH * kL;
  float2 acc[4][4];
#pragma unroll
  for (int i = 0; i < 4; i++)
#pragma unroll
    for (int j = 0; j < 4; j++) acc[i][j] = make_float2(0.f, 0.f);
  int ar = tid >> 2, ac = (tid & 3) * 4, bk = tid >> 4, bc = (tid & 15) * 4;
  for (int k0 = 0; k0 < kH; k0 += 16) {
    const float4* src = (const float4*)(ws_bbar + (size_t)(m0 + ar) * kH + k0 + ac);
    float4 v01 = src[0], v23 = src[1];
    As[ac + 0][ar] = make_float2(v01.x, v01.y);
    As[ac + 1][ar] = make_float2(v01.z, v01.w);
    As[ac + 2][ar] = make_float2(v23.x, v23.y);
    As[ac + 3][ar] = make_float2(v23.z, v23.w);
    float4 v = *(const float4*)(uB + (size_t)(k0 + bk) * kL + n0 + bc);
    *(float4*)&Bs[bk][bc] = v;
    __syncthreads();
#pragma unroll
    for (int kk = 0; kk < 16; ++kk) {
      const float4* arow = (const float4*)&As[kk][0];
      float4 a01 = arow[tm * 2 + 0], a23 = arow[tm * 2 + 1];
      float2 a[4] = {make_float2(a01.x, a01.y), make_float2(a01.z, a01.w),
                     make_float2(a23.x, a23.y), make_float2(a23.z, a23.w)};
      float4 bv = ((const float4*)&Bs[kk][0])[tn];
      float bbv[4] = {bv.x, bv.y, bv.z, bv.w};
#pragma unroll
      for (int mi = 0; mi < 4; mi++)
#pragma unroll
        for (int ni = 0; ni < 4; ni++) {
          acc[mi][ni].x = fmaf(a[mi].x, bbv[ni], acc[mi][ni].x);
          acc[mi][ni].y = fmaf(a[mi].y, bbv[ni], acc[mi][ni].y);
        }
    }
    __syncthreads();
  }
  float2* BuB = Bu + (size_t)b * kP * kL;
#pragma unroll
  for (int mi = 0; mi < 4; mi++) {
    int row = m0 + tm * 4 + mi;
    float2* dst = BuB + (size_t)row * kL + n0 + tn * 4;
    ((float4*)dst)[0] = make_float4(acc[mi][0].x, acc[mi][0].y, acc[mi][1].x, acc[mi][1].y);
    ((float4*)dst)[1] = make_float4(acc[mi][2].x, acc[mi][2].y, acc[mi][3].x, acc[mi][3].y);
  }
}

__global__ __launch_bounds__(256) void k_scanF(float2* __restrict__ Bu,
                                               const float2* __restrict__ Lbar) {
  int p = blockIdx.x & (kP - 1);
  int b = blockIdx.x >> 9;
  int tid = threadIdx.x, lane = tid & 63, w = tid >> 6;
  float2 lam = Lbar[p];
  float2* seq = Bu + ((size_t)b * kP + p) * kL;
  float2 v[16];
  const float4* src = (const float4*)(seq + tid * 16);
#pragma unroll
  for (int i = 0; i < 8; i++) {
    float4 t = src[i];
    v[2 * i] = make_float2(t.x, t.y);
    v[2 * i + 1] = make_float2(t.z, t.w);
  }
  float xr = 0.f, xi = 0.f;
#pragma unroll
  for (int i = 0; i < 16; i++) {
    float nr2 = fmaf(lam.x, xr, fmaf(-lam.y, xi, v[i].x));
    float ni2 = fmaf(lam.x, xi, fmaf(lam.y, xr, v[i].y));
    xr = nr2; xi = ni2;
  }
  float Ar = lam.x, Ai = lam.y;
#pragma unroll
  for (int s = 0; s < 4; s++) {
    float tr = Ar * Ar - Ai * Ai, ti = 2.f * Ar * Ai;
    Ar = tr; Ai = ti;
  }
  float br = xr, bi = xi;
  for (int off = 1; off < 64; off <<= 1) {
    float pAr = __shfl_up(Ar, off), pAi = __shfl_up(Ai, off);
    float pbr = __shfl_up(br, off), pbi = __shfl_up(bi, off);
    if (lane >= off) {
      float nAr = Ar * pAr - Ai * pAi, nAi = Ar * pAi + Ai * pAr;
      float nbr = Ar * pbr - Ai * pbi + br, nbi = Ar * pbi + Ai * pbr + bi;
      Ar = nAr; Ai = nAi; br = nbr; bi = nbi;
    }
  }
  __shared__ float4 wtot[4];
  if (lane == 63) wtot[w] = make_float4(Ar, Ai, br, bi);
  __syncthreads();
  float eAr = __shfl_up(Ar, 1), eAi = __shfl_up(Ai, 1);
  float ebr = __shfl_up(br, 1), ebi = __shfl_up(bi, 1);
  if (lane == 0) { eAr = 1.f; eAi = 0.f; ebr = 0.f; ebi = 0.f; }
  float pAr = 1.f, pAi = 0.f, pbr = 0.f, pbi = 0.f;
  for (int j = 0; j < w; j++) {
    float4 t = wtot[j];
    float nAr = t.x * pAr - t.y * pAi, nAi = t.x * pAi + t.y * pAr;
    float nbr = t.x * pbr - t.y * pbi + t.z, nbi = t.x * pbi + t.y * pbr + t.w;
    pAr = nAr; pAi = nAi; pbr = nbr; pbi = nbi;
  }
  float initr = eAr * pbr - eAi * pbi + ebr;
  float initi = eAr * pbi + eAi * pbr + ebi;
  xr = initr; xi = initi;
  float4* dst = (float4*)(seq + tid * 16);
#pragma unroll
  for (int i = 0; i < 8; i++) {
    float nr0 = fmaf(lam.x, xr, fmaf(-lam.y, xi, v[2 * i].x));
    float ni0 = fmaf(lam.x, xi, fmaf(lam.y, xr, v[2 * i].y));
    float nr1 = fmaf(lam.x, nr0, fmaf(-lam.y, ni0, v[2 * i + 1].x));
    float ni1 = fmaf(lam.x, ni0, fmaf(lam.y, nr0, v[2 * i + 1].y));
    dst[i] = make_float4(nr0, ni0, nr1, ni1);
    xr = nr1; xi = ni1;
  }
}

__global__ __launch_bounds__(256) void k_gemm2F(
    const float2* __restrict__ C, const float2* __restrict__ X,
    const float* __restrict__ u, const float* __restrict__ D,
    float* __restrict__ out) {
  __shared__ float2 As[16][64];
  __shared__ float2 Bs[16][64];
  int b = blockIdx.z, m0 = blockIdx.y * 64, n0 = blockIdx.x * 64;
  int tid = threadIdx.x, tn = tid & 15, tm = tid >> 4;
  const float2* Xb = X + (size_t)b * kP * kL;
  float acc[4][4];
#pragma unroll
  for (int i = 0; i < 4; i++)
#pragma unroll
    for (int j = 0; j < 4; j++) acc[i][j] = 0.f;
  int ar = tid >> 2, ac = (tid & 3) * 4, bk = tid >> 4, bc = (tid & 15) * 4;
  for (int k0 = 0; k0 < kP; k0 += 16) {
    const float4* src = (const float4*)(C + (size_t)(m0 + ar) * kP + k0 + ac);
    float4 v01 = src[0], v23 = src[1];
    As[ac + 0][ar] = make_float2(v01.x, v01.y);
    As[ac + 1][ar] = make_float2(v01.z, v01.w);
    As[ac + 2][ar] = make_float2(v23.x, v23.y);
    As[ac + 3][ar] = make_float2(v23.z, v23.w);
    const float4* srcb = (const float4*)(Xb + (size_t)(k0 + bk) * kL + n0 + bc);
    ((float4*)&Bs[bk][bc])[0] = srcb[0];
    ((float4*)&Bs[bk][bc])[1] = srcb[1];
    __syncthreads();
#pragma unroll
    for (int kk = 0; kk < 16; ++kk) {
      const float4* arow = (const float4*)&As[kk][0];
      float4 a01 = arow[tm * 2 + 0], a23 = arow[tm * 2 + 1];
      float2 a[4] = {make_float2(a01.x, a01.y), make_float2(a01.z, a01.w),
                     make_float2(a23.x, a23.y), make_float2(a23.z, a23.w)};
      const float4* brow = (const float4*)&Bs[kk][0];
      float4 b01 = brow[tn * 2 + 0], b23 = brow[tn * 2 + 1];
      float2 bbv[4] = {make_float2(b01.x, b01.y), make_float2(b01.z, b01.w),
                       make_float2(b23.x, b23.y), make_float2(b23.z, b23.w)};
#pragma unroll
      for (int mi = 0; mi < 4; mi++)
#pragma unroll
        for (int ni = 0; ni < 4; ni++) {
          acc[mi][ni] = fmaf(a[mi].x, bbv[ni].x, acc[mi][ni]);
          acc[mi][ni] = fmaf(-a[mi].y, bbv[ni].y, acc[mi][ni]);
        }
    }
    __syncthreads();
  }
#pragma unroll
  for (int mi = 0; mi < 4; mi++) {
    int h = m0 + tm * 4 + mi;
    float d = D[h];
    const float* urow = u + ((size_t)b * kH + h) * kL + n0 + tn * 4;
    float4 uv = *(const float4*)urow;
    float uu[4] = {uv.x, uv.y, uv.z, uv.w};
    float res[4];
#pragma unroll
    for (int ni = 0; ni < 4; ni++) {
      float y = 2.f * acc[mi][ni] + d * uu[ni];
      res[ni] = 0.5f * y * (1.f + erff(y * 0.70710678118654752f));
    }
    float* orow = out + ((size_t)b * kH + h) * kL + n0 + tn * 4;
    *(float4*)orow = make_float4(res[0], res[1], res[2], res[3]);
  }
}

// ---------------------------------------------------------------- launch
extern "C" void kernel_launch(void* const* d_in, const int* in_sizes, int n_in,
                              void* d_out, int out_size, void* d_ws, size_t ws_size,
                              hipStream_t stream) {
  const float* input_sequence = (const float*)d_in[0];
  const float* Lambda_re = (const float*)d_in[2];
  const float* Lambda_im = (const float*)d_in[3];
  const float* B = (const float*)d_in[4];
  const float* C = (const float*)d_in[5];
  const float* D = (const float*)d_in[6];
  const float* log_step = (const float*)d_in[7];
  float* out = (float*)d_out;

  if (ws_size >= MID_BYTES) {
    unsigned char* ws = (unsigned char*)d_ws;
    unsigned short* a1h = (unsigned short*)(ws + A1H_OFF);
    unsigned short* a2h = (unsigned short*)(ws + A2H_OFF);
    float2* lbar = (float2*)(ws + LBAR_B);
    float* bu = (float*)(ws + BU_B);
    unsigned short* th = (unsigned short*)(ws + TH_B);

    k_prep1<<<dim3(kP), 256, 0, stream>>>(Lambda_re, Lambda_im, B, log_step, ws);
    k_prep2<<<dim3(kH), 256, 0, stream>>>(C, ws);

    dim3 tgrid(kL / 64, 1024 / 64, kB);
    dim3 ggrid(kN / 256, kM / 256, kB);  // 16 x 4 x 4 = 256 blocks, 1/CU

    k_transpose<<<tgrid, 256, 0, stream>>>(input_sequence, th);
    k_gemm8<false><<<ggrid, 512, 0, stream>>>(a1h, th, bu, nullptr, nullptr);
    k_scan<<<dim3(kB * kP), 256, 0, stream>>>(bu, lbar);
    k_transpose<<<tgrid, 256, 0, stream>>>(bu, th);
    k_gemm8<true><<<ggrid, 512, 0, stream>>>(a2h, th, out, input_sequence, D);
  } else {
    // fp32 fallback (round-1 path)
    float2* ws = (float2*)d_ws;
    float2* Bbar = ws + OBBAR;
    float2* Lbar = ws + OLBAR;
    float2* Bu = ws + OBU;
    k_precomputeF<<<dim3(kP), 256, 0, stream>>>(Lambda_re, Lambda_im, B, log_step, ws);
    k_gemm1F<<<dim3(kL / 64, kP / 64, kB), 256, 0, stream>>>(Bbar, input_sequence, Bu);
    k_scanF<<<dim3(kB * kP), 256, 0, stream>>>(Bu, Lbar);
    k_gemm2F<<<dim3(kL / 64, kH / 64, kB), 256, 0, stream>>>(
        (const float2*)C, (const float2*)Bu, input_sequence, D, out);
  }
}

// Round 3
// 291.103 us; speedup vs baseline: 1.0730x; 1.0124x over previous
//
#include <hip/hip_runtime.h>
#include <math.h>

// S5 SSM forward — R8: 128x256-tile BK=32 8-phase MFMA GEMMs at 2 blocks/CU.
// R7 post-mortem: 256² tile capped at 2 waves/SIMD (248 regs/wave, 128KiB LDS)
// -> every gate/barrier stall exposed. R8 shrinks per-wave state (acc 64 VGPR,
// LDS 48KiB) so 2 blocks co-reside per CU (16 waves/CU) and stalls overlap.
// Same T2 st_16x32 swizzle (verified 0 bank conflicts in R7), same counted-vmcnt
// gate discipline, same setprio.
// BSZ=4, L=4096, H=1024, P=512.

constexpr int kB = 4, kL = 4096, kH = 1024, kP = 512;
constexpr int kM = 1024, kK = 1024, kN = 4096;

typedef short bf16x8 __attribute__((ext_vector_type(8)));
typedef float f32x4 __attribute__((ext_vector_type(4)));

// ---- ws layout (bytes), MFMA path
constexpr size_t A1H_OFF = 0;                                    // 2 MiB
constexpr size_t A2H_OFF = A1H_OFF + (size_t)kM * kK * 2;        // 2 MiB
constexpr size_t LBAR_B  = A2H_OFF + (size_t)kM * kK * 2;        // 4 KiB
constexpr size_t BU_B    = (LBAR_B + 4096 + 255) & ~(size_t)255; // 64 MiB fp32
constexpr size_t TH_B    = BU_B + (size_t)kB * kM * kN * 4;      // 32 MiB bf16
constexpr size_t MID_BYTES = TH_B + (size_t)kB * kN * kK * 2;    // ~100 MiB

// ---- bf16 helpers
__device__ __forceinline__ unsigned short f2bf(float x) {
  unsigned int u = __float_as_uint(x);
  u += 0x7fffu + ((u >> 16) & 1u);
  return (unsigned short)(u >> 16);
}
__device__ __forceinline__ float bf2f(unsigned short h) {
  return __uint_as_float(((unsigned int)h) << 16);
}

__device__ __forceinline__ void gl2lds16(const void* g, void* l) {
  __builtin_amdgcn_global_load_lds(
      (const __attribute__((address_space(1))) void*)g,
      (__attribute__((address_space(3))) void*)l, 16, 0, 0);
}

// s_waitcnt with vmcnt=N, lgkmcnt/expcnt = don't-care
template <int N>
__device__ __forceinline__ void wait_vm() {
  __builtin_amdgcn_s_waitcnt((N & 15) | ((N >> 4) << 14) | (15 << 8) | (7 << 4));
}

// ---------------------------------------------------------------- prep1
__global__ __launch_bounds__(256) void k_prep1(
    const float* __restrict__ Lre, const float* __restrict__ Lim,
    const float* __restrict__ B, const float* __restrict__ log_step,
    unsigned char* __restrict__ ws) {
  int p = blockIdx.x;
  float lr = Lre[p], li = Lim[p];
  float step = expf(log_step[p]);
  float er = expf(lr * step);
  float sb, cb;
  sincosf(li * step, &sb, &cb);
  float lbr = er * cb, lbi = er * sb;
  float nr = lbr - 1.0f, ni = lbi;
  float inv = 1.0f / (lr * lr + li * li);
  float sr = (nr * lr + ni * li) * inv;
  float si = (ni * lr - nr * li) * inv;

  if (threadIdx.x == 0) ((float2*)(ws + LBAR_B))[p] = make_float2(lbr, lbi);

  unsigned short* a1h = (unsigned short*)(ws + A1H_OFF);
  const float* Brow = B + (size_t)p * kH * 2;
  for (int h = threadIdx.x; h < kH; h += 256) {
    float br = Brow[2 * h], bi = Brow[2 * h + 1];
    a1h[(size_t)p * kK + h] = f2bf(sr * br - si * bi);
    a1h[(size_t)(kP + p) * kK + h] = f2bf(sr * bi + si * br);
  }
}

// ---------------------------------------------------------------- prep2
// A2[h][k] = 2*Cr[h][k] (k<512) | -2*Ci[h][k-512]
__global__ __launch_bounds__(256) void k_prep2(
    const float* __restrict__ C, unsigned char* __restrict__ ws) {
  int h = blockIdx.x;
  unsigned short* a2h = (unsigned short*)(ws + A2H_OFF);
  for (int k = threadIdx.x; k < kK; k += 256) {
    float v = (k < kP) ? 2.f * C[((size_t)h * kP + k) * 2]
                       : -2.f * C[((size_t)h * kP + (k - kP)) * 2 + 1];
    a2h[(size_t)h * kK + k] = f2bf(v);
  }
}

// ---------------------------------------------------------------- transpose (fp32 -> bf16T)
// in: fp32 [b][1024][4096] -> out: bf16 [b][4096][1024]   [replay-proven]
__global__ __launch_bounds__(256) void k_transpose(
    const float* __restrict__ in, unsigned short* __restrict__ oh) {
  __shared__ float t[64][65];
  int b = blockIdx.z;
  int r0 = blockIdx.y * 64;
  int c0 = blockIdx.x * 64;
  int tid = threadIdx.x;
  const float* src = in + ((size_t)b * 1024 + r0) * 4096 + c0;
  int cc = (tid & 15) * 4, rr = tid >> 4;
#pragma unroll
  for (int i = 0; i < 4; i++) {
    float4 v = *(const float4*)(src + (size_t)(rr + i * 16) * 4096 + cc);
    t[rr + i * 16][cc + 0] = v.x;
    t[rr + i * 16][cc + 1] = v.y;
    t[rr + i * 16][cc + 2] = v.z;
    t[rr + i * 16][cc + 3] = v.w;
  }
  __syncthreads();
  int oc = tid >> 2;
  int og = (tid & 3) * 2;
#pragma unroll
  for (int i = 0; i < 2; i++) {
    int g = og + i;
    unsigned short hv[8];
#pragma unroll
    for (int j = 0; j < 8; j++) hv[j] = f2bf(t[g * 8 + j][oc]);
    size_t ob = ((size_t)b * 4096 + c0 + oc) * 1024 + r0 + g * 8;
    *(uint4*)(oh + ob) = *(uint4*)hv;
  }
}

// ================================================================ 8-phase GEMM
// Tile 128(M) x 256(N), BK=32, 512 threads = 8 waves (2M x 4N), per-wave 64x64.
// LDS 48 KiB: A[2][128][32] (8KB each) + B[2][256][32] (16KB each), stored as
// 16x32-element subtiles (1024 B) with st_16x32 swizzle byte^=((byte>>9)&1)<<5.
// Staging via global_load_lds with LINEAR dest + inverse-swizzled global src
// (rule #21; involution verified: read XOR cancels store XOR exactly).
// One 8KB piece per stage call = 1 gl_lds instr/thread -> clean vmcnt counting.

// linear LDS byte Dp within an 8KB piece (128 rows x 32 k) -> source element
// offset (row*kK + k) whose swizzled position is Dp.
__device__ __forceinline__ int stage_src_off32(int Dp) {
  int Ds = Dp ^ (((Dp >> 9) & 1) << 5);  // involution
  int s = Ds >> 10, d = Ds & 1023;       // subtile (row-block), within-subtile
  int row = (s << 4) + (d >> 6);         // 0..127
  int kk = (d & 63) >> 1;                // 0..31 (multiple of 8)
  return row * kK + kk;
}

// fragment reads: lane (q,r) reads rows base+r, k=8q of subtile RB
template <int MH>
__device__ __forceinline__ void rd_a2(bf16x8 (&a)[2], const unsigned char* lds,
                                      int base, int wmrb, int lane_off) {
#pragma unroll
  for (int i = 0; i < 2; i++)
    a[i] = *(const bf16x8*)(lds + base + ((wmrb + MH * 2 + i) << 10) + lane_off);
}
template <int NH>
__device__ __forceinline__ void rd_b2(bf16x8 (&bb)[2][2], const unsigned char* lds,
                                      int base, int wnrb, int lane_off) {
#pragma unroll
  for (int i = 0; i < 2; i++)
    bb[NH][i] = *(const bf16x8*)(lds + base + ((wnrb + NH * 2 + i) << 10) + lane_off);
}

template <int MH, int NH>
__device__ __forceinline__ void quad4(f32x4 (&acc)[4][4], bf16x8 (&a)[2],
                                      bf16x8 (&bb)[2][2]) {
  __builtin_amdgcn_s_setprio(1);
#pragma unroll
  for (int mi = 0; mi < 2; mi++)
#pragma unroll
    for (int nj = 0; nj < 2; nj++)
      acc[MH * 2 + mi][NH * 2 + nj] = __builtin_amdgcn_mfma_f32_16x16x32_bf16(
          a[mi], bb[NH][nj], acc[MH * 2 + mi][NH * 2 + nj], 0, 0, 0);
  __builtin_amdgcn_s_setprio(0);
}

#define BAR __builtin_amdgcn_s_barrier()
#define LGKM0                                           \
  do {                                                  \
    asm volatile("s_waitcnt lgkmcnt(0)" ::: "memory");  \
    __builtin_amdgcn_sched_barrier(0);                  \
  } while (0)

template <bool EPI>
__global__ __launch_bounds__(512, 4) void k_gemm32(
    const unsigned short* __restrict__ Ah, const unsigned short* __restrict__ Bh,
    float* __restrict__ out, const float* __restrict__ u,
    const float* __restrict__ D) {
  __shared__ __align__(16) unsigned char lds[49152];
  constexpr int LA0 = 0, LA1 = 8192, LB0 = 16384, LB1 = 32768;
  constexpr int NT2 = kK / 64;  // 16 iterations, 2 K-tiles (BK=32) each

  int b = blockIdx.z;
  int m0 = blockIdx.y * 128, n0 = blockIdx.x * 256;
  int tid = threadIdx.x, w = tid >> 6;
  int q = (tid >> 4) & 3, r = tid & 15;
  int wm = (w >> 2) * 64, wn = (w & 3) * 64;
  int wmrb = (w >> 2) * 4, wnrb = (w & 3) * 4;
  int lane_off = (r * 64 + q * 16) ^ ((r & 8) << 2);  // st_16x32 read swizzle

  int d0 = tid << 4;
  int rowk = stage_src_off32(d0);  // same decode for A piece and each B half

  const unsigned short* pA = Ah + (size_t)m0 * kK;
  const unsigned short* pB = Bh + (size_t)b * kN * kK + (size_t)n0 * kK;

  f32x4 acc[4][4] = {};
  bf16x8 a[2], bb[2][2];

  // stage helpers: 1 gl_lds per thread each (A piece 8KB; B half 8KB)
#define STG_A(KT, LB)                                             \
  gl2lds16(pA + (KT) * 32 + rowk, lds + (LB) + d0)
#define STG_B(H, KT, LB)                                          \
  gl2lds16(pB + (size_t)(H) * 128 * kK + (KT) * 32 + rowk,        \
           lds + (LB) + (H) * 8192 + d0)

  // prologue FIFO: [A0(kt0), B0h0, B0h1, B1h0(kt1), B1h1] -> wait 2 = buf0 ready
  STG_A(0, LA0);
  STG_B(0, 0, LB0); STG_B(1, 0, LB0);
  STG_B(0, 1, LB1); STG_B(1, 1, LB1);
  wait_vm<2>();
  BAR;

  for (int it = 0; it < NT2; ++it) {
    int kt = it * 2;
    bool pf = (it + 1 < NT2);
    // -------- phases 1-4: compute buf0 (K-tile kt)
    // ph1: (mlo,nlo); stage buf1.A (kt+1)  [LA1 last read prev ph7]
    rd_a2<0>(a, lds, LA0, wmrb, lane_off);
    rd_b2<0>(bb, lds, LB0, wnrb, lane_off);
    STG_A(kt + 1, LA1);
    BAR; LGKM0; quad4<0, 0>(acc, a, bb); BAR;
    // ph2: (mlo,nhi)
    rd_b2<1>(bb, lds, LB0, wnrb, lane_off);
    BAR; LGKM0; quad4<0, 1>(acc, a, bb); BAR;
    // ph3: (mhi,nhi); stage buf0.B.h0 (kt+2)  [LB0 last read ph2]
    rd_a2<1>(a, lds, LA0, wmrb, lane_off);
    if (pf) STG_B(0, kt + 2, LB0);
    BAR; LGKM0; quad4<1, 1>(acc, a, bb); BAR;
    // ph4: (mhi,nlo) reuses regs; stage buf0.B.h1; GATE buf1
    // FIFO: [B1h0(prev p7), B1h1(prev p8), A1(p1), B0h0(p3), B0h1(p4)] wait 2
    if (pf) STG_B(1, kt + 2, LB0);
    BAR; quad4<1, 0>(acc, a, bb);
    if (pf) wait_vm<2>(); else wait_vm<0>();
    BAR;
    // -------- phases 5-8: compute buf1 (K-tile kt+1)
    // ph5: (mlo,nlo); stage buf0.A (kt+2)  [LA0 last read ph3]
    rd_a2<0>(a, lds, LA1, wmrb, lane_off);
    rd_b2<0>(bb, lds, LB1, wnrb, lane_off);
    if (pf) STG_A(kt + 2, LA0);
    BAR; LGKM0; quad4<0, 0>(acc, a, bb); BAR;
    // ph6: (mlo,nhi)
    rd_b2<1>(bb, lds, LB1, wnrb, lane_off);
    BAR; LGKM0; quad4<0, 1>(acc, a, bb); BAR;
    // ph7: (mhi,nhi); stage buf1.B.h0 (kt+3)  [LB1 last read ph6]
    rd_a2<1>(a, lds, LA1, wmrb, lane_off);
    if (pf) STG_B(0, kt + 3, LB1);
    BAR; LGKM0; quad4<1, 1>(acc, a, bb); BAR;
    // ph8: (mhi,nlo); stage buf1.B.h1; GATE buf0(kt+2)
    // FIFO: [B0h0(p3), B0h1(p4), A0(p5), B1h0(p7), B1h1(p8)] wait 2
    if (pf) STG_B(1, kt + 3, LB1);
    BAR; quad4<1, 0>(acc, a, bb);
    if (pf) wait_vm<2>();
    BAR;
  }
#undef STG_A
#undef STG_B

  // C/D layout: col = r, row = q*4 + reg
#pragma unroll
  for (int mi = 0; mi < 4; mi++) {
#pragma unroll
    for (int reg = 0; reg < 4; reg++) {
      int row = m0 + wm + mi * 16 + q * 4 + reg;
      float dv = EPI ? D[row] : 0.f;
#pragma unroll
      for (int ni = 0; ni < 4; ni++) {
        int col = n0 + wn + ni * 16 + r;
        size_t o = ((size_t)b * kM + row) * (size_t)kN + col;
        float v = acc[mi][ni][reg];
        if (EPI) {
          float y = v + dv * u[o];
          v = 0.5f * y * (1.f + erff(y * 0.70710678118654752f));
        }
        out[o] = v;
      }
    }
  }
}

// ---------------------------------------------------------------- scan (fp32 planar, in-place)
// [replay-proven]
__global__ __launch_bounds__(256) void k_scan(float* __restrict__ bu,
                                              const float2* __restrict__ lbar) {
  int p = blockIdx.x & (kP - 1);
  int b = blockIdx.x >> 9;
  int tid = threadIdx.x, lane = tid & 63, w = tid >> 6;
  float2 lam = lbar[p];
  float* sre = bu + ((size_t)b * kM + p) * (size_t)kN;
  float* sim = sre + (size_t)kP * kN;

  float vr[16], vi[16];
  {
    const float4* pr = (const float4*)(sre + tid * 16);
    const float4* pi = (const float4*)(sim + tid * 16);
#pragma unroll
    for (int i = 0; i < 4; i++) {
      float4 a = pr[i], c = pi[i];
      vr[4 * i] = a.x; vr[4 * i + 1] = a.y; vr[4 * i + 2] = a.z; vr[4 * i + 3] = a.w;
      vi[4 * i] = c.x; vi[4 * i + 1] = c.y; vi[4 * i + 2] = c.z; vi[4 * i + 3] = c.w;
    }
  }

  float xr = 0.f, xi = 0.f;
#pragma unroll
  for (int i = 0; i < 16; i++) {
    float nr2 = fmaf(lam.x, xr, fmaf(-lam.y, xi, vr[i]));
    float ni2 = fmaf(lam.x, xi, fmaf(lam.y, xr, vi[i]));
    xr = nr2; xi = ni2;
  }

  float Ar = lam.x, Ai = lam.y;
#pragma unroll
  for (int s = 0; s < 4; s++) {
    float tr = Ar * Ar - Ai * Ai, ti = 2.f * Ar * Ai;
    Ar = tr; Ai = ti;
  }
  float br = xr, bi = xi;

  for (int off = 1; off < 64; off <<= 1) {
    float pAr = __shfl_up(Ar, off), pAi = __shfl_up(Ai, off);
    float pbr = __shfl_up(br, off), pbi = __shfl_up(bi, off);
    if (lane >= off) {
      float nAr = Ar * pAr - Ai * pAi;
      float nAi = Ar * pAi + Ai * pAr;
      float nbr = Ar * pbr - Ai * pbi + br;
      float nbi = Ar * pbi + Ai * pbr + bi;
      Ar = nAr; Ai = nAi; br = nbr; bi = nbi;
    }
  }

  __shared__ float4 wtot[4];
  if (lane == 63) wtot[w] = make_float4(Ar, Ai, br, bi);
  __syncthreads();

  float eAr = __shfl_up(Ar, 1), eAi = __shfl_up(Ai, 1);
  float ebr = __shfl_up(br, 1), ebi = __shfl_up(bi, 1);
  if (lane == 0) { eAr = 1.f; eAi = 0.f; ebr = 0.f; ebi = 0.f; }

  float pAr = 1.f, pAi = 0.f, pbr = 0.f, pbi = 0.f;
  for (int j = 0; j < w; j++) {
    float4 t = wtot[j];
    float nAr = t.x * pAr - t.y * pAi;
    float nAi = t.x * pAi + t.y * pAr;
    float nbr = t.x * pbr - t.y * pbi + t.z;
    float nbi = t.x * pbi + t.y * pbr + t.w;
    pAr = nAr; pAi = nAi; pbr = nbr; pbi = nbi;
  }

  float initr = eAr * pbr - eAi * pbi + ebr;
  float initi = eAr * pbi + eAi * pbr + ebi;

  xr = initr; xi = initi;
  float4* qr = (float4*)(sre + tid * 16);
  float4* qi = (float4*)(sim + tid * 16);
#pragma unroll
  for (int i = 0; i < 4; i++) {
    float rr[4], ii[4];
#pragma unroll
    for (int j = 0; j < 4; j++) {
      float nr2 = fmaf(lam.x, xr, fmaf(-lam.y, xi, vr[4 * i + j]));
      float ni2 = fmaf(lam.x, xi, fmaf(lam.y, xr, vi[4 * i + j]));
      xr = nr2; xi = ni2; rr[j] = nr2; ii[j] = ni2;
    }
    qr[i] = make_float4(rr[0], rr[1], rr[2], rr[3]);
    qi[i] = make_float4(ii[0], ii[1], ii[2], ii[3]);
  }
}

// ================================================================ fp32 fallback
constexpr size_t OBBAR = 0;
constexpr size_t OLBAR = (size_t)kP * kH;
constexpr size_t OBU = OLBAR + 1024;

__global__ __launch_bounds__(256) void k_precomputeF(
    const float* __restrict__ Lre, const float* __restrict__ Lim,
    const float* __restrict__ B, const float* __restrict__ log_step,
    float2* __restrict__ ws) {
  int p = blockIdx.x;
  float lr = Lre[p], li = Lim[p];
  float step = expf(log_step[p]);
  float er = expf(lr * step);
  float sb, cb;
  sincosf(li * step, &sb, &cb);
  float lbr = er * cb, lbi = er * sb;
  float nr = lbr - 1.0f, ni = lbi;
  float inv = 1.0f / (lr * lr + li * li);
  float sr = (nr * lr + ni * li) * inv;
  float si = (ni * lr - nr * li) * inv;
  if (threadIdx.x == 0) ws[OLBAR + p] = make_float2(lbr, lbi);
  float2* Bbar = ws + OBBAR;
  const float* Brow = B + (size_t)p * kH * 2;
  for (int h = threadIdx.x; h < kH; h += 256) {
    float br = Brow[2 * h], bi = Brow[2 * h + 1];
    Bbar[(size_t)p * kH + h] = make_float2(sr * br - si * bi, sr * bi + si * br);
  }
}

__global__ __launch_bounds__(256) void k_gemm1F(
    const float2* __restrict__ ws_bbar, const float* __restrict__ u,
    float2* __restrict__ Bu) {
  __shared__ float2 As[16][64];
  __shared__ float Bs[16][64];
  int b = blockIdx.z, m0 = blockIdx.y * 64, n0 = blockIdx.x * 64;
  int tid = threadIdx.x, tn = tid & 15, tm = tid >> 4;
  const float* uB = u + (size_t)b * kH * kL;
  float2 acc[4][4];
#pragma unroll
  for (int i = 0; i < 4; i++)
#pragma unroll
    for (int j = 0; j < 4; j++) acc[i][j] = make_float2(0.f, 0.f);
  int ar = tid >> 2, ac = (tid & 3) * 4, bk = tid >> 4, bc = (tid & 15) * 4;
  for (int k0 = 0; k0 < kH; k0 += 16) {
    const float4* src = (const float4*)(ws_bbar + (size_t)(m0 + ar) * kH + k0 + ac);
    float4 v01 = src[0], v23 = src[1];
    As[ac + 0][ar] = make_float2(v01.x, v01.y);
    As[ac + 1][ar] = make_float2(v01.z, v01.w);
    As[ac + 2][ar] = make_float2(v23.x, v23.y);
    As[ac + 3][ar] = make_float2(v23.z, v23.w);
    float4 v = *(const float4*)(uB + (size_t)(k0 + bk) * kL + n0 + bc);
    *(float4*)&Bs[bk][bc] = v;
    __syncthreads();
#pragma unroll
    for (int kk = 0; kk < 16; ++kk) {
      const float4* arow = (const float4*)&As[kk][0];
      float4 a01 = arow[tm * 2 + 0], a23 = arow[tm * 2 + 1];
      float2 a[4] = {make_float2(a01.x, a01.y), make_float2(a01.z, a01.w),
                     make_float2(a23.x, a23.y), make_float2(a23.z, a23.w)};
      float4 bv = ((const float4*)&Bs[kk][0])[tn];
      float bbv[4] = {bv.x, bv.y, bv.z, bv.w};
#pragma unroll
      for (int mi = 0; mi < 4; mi++)
#pragma unroll
        for (int ni = 0; ni < 4; ni++) {
          acc[mi][ni].x = fmaf(a[mi].x, bbv[ni], acc[mi][ni].x);
          acc[mi][ni].y = fmaf(a[mi].y, bbv[ni], acc[mi][ni].y);
        }
    }
    __syncthreads();
  }
  float2* BuB = Bu + (size_t)b * kP * kL;
#pragma unroll
  for (int mi = 0; mi < 4; mi++) {
    int row = m0 + tm * 4 + mi;
    float2* dst = BuB + (size_t)row * kL + n0 + tn * 4;
    ((float4*)dst)[0] = make_float4(acc[mi][0].x, acc[mi][0].y, acc[mi][1].x, acc[mi][1].y);
    ((float4*)dst)[1] = make_float4(acc[mi][2].x, acc[mi][2].y, acc[mi][3].x, acc[mi][3].y);
  }
}

__global__ __launch_bounds__(256) void k_scanF(float2* __restrict__ Bu,
                                               const float2* __restrict__ Lbar) {
  int p = blockIdx.x & (kP - 1);
  int b = blockIdx.x >> 9;
  int tid = threadIdx.x, lane = tid & 63, w = tid >> 6;
  float2 lam = Lbar[p];
  float2* seq = Bu + ((size_t)b * kP + p) * kL;
  float2 v[16];
  const float4* src = (const float4*)(seq + tid * 16);
#pragma unroll
  for (int i = 0; i < 8; i++) {
    float4 t = src[i];
    v[2 * i] = make_float2(t.x, t.y);
    v[2 * i + 1] = make_float2(t.z, t.w);
  }
  float xr = 0.f, xi = 0.f;
#pragma unroll
  for (int i = 0; i < 16; i++) {
    float nr2 = fmaf(lam.x, xr, fmaf(-lam.y, xi, v[i].x));
    float ni2 = fmaf(lam.x, xi, fmaf(lam.y, xr, v[i].y));
    xr = nr2; xi = ni2;
  }
  float Ar = lam.x, Ai = lam.y;
#pragma unroll
  for (int s = 0; s < 4; s++) {
    float tr = Ar * Ar - Ai * Ai, ti = 2.f * Ar * Ai;
    Ar = tr; Ai = ti;
  }
  float br = xr, bi = xi;
  for (int off = 1; off < 64; off <<= 1) {
    float pAr = __shfl_up(Ar, off), pAi = __shfl_up(Ai, off);
    float pbr = __shfl_up(br, off), pbi = __shfl_up(bi, off);
    if (lane >= off) {
      float nAr = Ar * pAr - Ai * pAi, nAi = Ar * pAi + Ai * pAr;
      float nbr = Ar * pbr - Ai * pbi + br, nbi = Ar * pbi + Ai * pbr + bi;
      Ar = nAr; Ai = nAi; br = nbr; bi = nbi;
    }
  }
  __shared__ float4 wtot[4];
  if (lane == 63) wtot[w] = make_float4(Ar, Ai, br, bi);
  __syncthreads();
  float eAr = __shfl_up(Ar, 1), eAi = __shfl_up(Ai, 1);
  float ebr = __shfl_up(br, 1), ebi = __shfl_up(bi, 1);
  if (lane == 0) { eAr = 1.f; eAi = 0.f; ebr = 0.f; ebi = 0.f; }
  float pAr = 1.f, pAi = 0.f, pbr = 0.f, pbi = 0.f;
  for (int j = 0; j < w; j++) {
    float4 t = wtot[j];
    float nAr = t.x * pAr - t.y * pAi, nAi = t.x * pAi + t.y * pAr;
    float nbr = t.x * pbr - t.y * pbi + t.z, nbi = t.x * pbi + t.y * pbr + t.w;
    pAr = nAr; pAi = nAi; pbr = nbr; pbi = nbi;
  }
  float initr = eAr * pbr - eAi * pbi + ebr;
  float initi = eAr * pbi + eAi * pbr + ebi;
  xr = initr; xi = initi;
  float4* dst = (float4*)(seq + tid * 16);
#pragma unroll
  for (int i = 0; i < 8; i++) {
    float nr0 = fmaf(lam.x, xr, fmaf(-lam.y, xi, v[2 * i].x));
    float ni0 = fmaf(lam.x, xi, fmaf(lam.y, xr, v[2 * i].y));
    float nr1 = fmaf(lam.x, nr0, fmaf(-lam.y, ni0, v[2 * i + 1].x));
    float ni1 = fmaf(lam.x, ni0, fmaf(lam.y, nr0, v[2 * i + 1].y));
    dst[i] = make_float4(nr0, ni0, nr1, ni1);
    xr = nr1; xi = ni1;
  }
}

__global__ __launch_bounds__(256) void k_gemm2F(
    const float2* __restrict__ C, const float2* __restrict__ X,
    const float* __restrict__ u, const float* __restrict__ D,
    float* __restrict__ out) {
  __shared__ float2 As[16][64];
  __shared__ float2 Bs[16][64];
  int b = blockIdx.z, m0 = blockIdx.y * 64, n0 = blockIdx.x * 64;
  int tid = threadIdx.x, tn = tid & 15, tm = tid >> 4;
  const float2* Xb = X + (size_t)b * kP * kL;
  float acc[4][4];
#pragma unroll
  for (int i = 0; i < 4; i++)
#pragma unroll
    for (int j = 0; j < 4; j++) acc[i][j] = 0.f;
  int ar = tid >> 2, ac = (tid & 3) * 4, bk = tid >> 4, bc = (tid & 15) * 4;
  for (int k0 = 0; k0 < kP; k0 += 16) {
    const float4* src = (const float4*)(C + (size_t)(m0 + ar) * kP + k0 + ac);
    float4 v01 = src[0], v23 = src[1];
    As[ac + 0][ar] = make_float2(v01.x, v01.y);
    As[ac + 1][ar] = make_float2(v01.z, v01.w);
    As[ac + 2][ar] = make_float2(v23.x, v23.y);
    As[ac + 3][ar] = make_float2(v23.z, v23.w);
    const float4* srcb = (const float4*)(Xb + (size_t)(k0 + bk) * kL + n0 + bc);
    ((float4*)&Bs[bk][bc])[0] = srcb[0];
    ((float4*)&Bs[bk][bc])[1] = srcb[1];
    __syncthreads();
#pragma unroll
    for (int kk = 0; kk < 16; ++kk) {
      const float4* arow = (const float4*)&As[kk][0];
      float4 a01 = arow[tm * 2 + 0], a23 = arow[tm * 2 + 1];
      float2 a[4] = {make_float2(a01.x, a01.y), make_float2(a01.z, a01.w),
                     make_float2(a23.x, a23.y), make_float2(a23.z, a23.w)};
      const float4* brow = (const float4*)&Bs[kk][0];
      float4 b01 = brow[tn * 2 + 0], b23 = brow[tn * 2 + 1];
      float2 bbv[4] = {make_float2(b01.x, b01.y), make_float2(b01.z, b01.w),
                       make_float2(b23.x, b23.y), make_float2(b23.z, b23.w)};
#pragma unroll
      for (int mi = 0; mi < 4; mi++)
#pragma unroll
        for (int ni = 0; ni < 4; ni++) {
          acc[mi][ni] = fmaf(a[mi].x, bbv[ni].x, acc[mi][ni]);
          acc[mi][ni] = fmaf(-a[mi].y, bbv[ni].y, acc[mi][ni]);
        }
    }
    __syncthreads();
  }
#pragma unroll
  for (int mi = 0; mi < 4; mi++) {
    int h = m0 + tm * 4 + mi;
    float d = D[h];
    const float* urow = u + ((size_t)b * kH + h) * kL + n0 + tn * 4;
    float4 uv = *(const float4*)urow;
    float uu[4] = {uv.x, uv.y, uv.z, uv.w};
    float res[4];
#pragma unroll
    for (int ni = 0; ni < 4; ni++) {
      float y = 2.f * acc[mi][ni] + d * uu[ni];
      res[ni] = 0.5f * y * (1.f + erff(y * 0.70710678118654752f));
    }
    float* orow = out + ((size_t)b * kH + h) * kL + n0 + tn * 4;
    *(float4*)orow = make_float4(res[0], res[1], res[2], res[3]);
  }
}

// ---------------------------------------------------------------- launch
extern "C" void kernel_launch(void* const* d_in, const int* in_sizes, int n_in,
                              void* d_out, int out_size, void* d_ws, size_t ws_size,
                              hipStream_t stream) {
  const float* input_sequence = (const float*)d_in[0];
  const float* Lambda_re = (const float*)d_in[2];
  const float* Lambda_im = (const float*)d_in[3];
  const float* B = (const float*)d_in[4];
  const float* C = (const float*)d_in[5];
  const float* D = (const float*)d_in[6];
  const float* log_step = (const float*)d_in[7];
  float* out = (float*)d_out;

  if (ws_size >= MID_BYTES) {
    unsigned char* ws = (unsigned char*)d_ws;
    unsigned short* a1h = (unsigned short*)(ws + A1H_OFF);
    unsigned short* a2h = (unsigned short*)(ws + A2H_OFF);
    float2* lbar = (float2*)(ws + LBAR_B);
    float* bu = (float*)(ws + BU_B);
    unsigned short* th = (unsigned short*)(ws + TH_B);

    k_prep1<<<dim3(kP), 256, 0, stream>>>(Lambda_re, Lambda_im, B, log_step, ws);
    k_prep2<<<dim3(kH), 256, 0, stream>>>(C, ws);

    dim3 tgrid(kL / 64, 1024 / 64, kB);
    dim3 ggrid(kN / 256, kM / 128, kB);  // 16 x 8 x 4 = 512 blocks, 2/CU

    k_transpose<<<tgrid, 256, 0, stream>>>(input_sequence, th);
    k_gemm32<false><<<ggrid, 512, 0, stream>>>(a1h, th, bu, nullptr, nullptr);
    k_scan<<<dim3(kB * kP), 256, 0, stream>>>(bu, lbar);
    k_transpose<<<tgrid, 256, 0, stream>>>(bu, th);
    k_gemm32<true><<<ggrid, 512, 0, stream>>>(a2h, th, out, input_sequence, D);
  } else {
    // fp32 fallback (round-1 path)
    float2* ws = (float2*)d_ws;
    float2* Bbar = ws + OBBAR;
    float2* Lbar = ws + OLBAR;
    float2* Bu = ws + OBU;
    k_precomputeF<<<dim3(kP), 256, 0, stream>>>(Lambda_re, Lambda_im, B, log_step, ws);
    k_gemm1F<<<dim3(kL / 64, kP / 64, kB), 256, 0, stream>>>(Bbar, input_sequence, Bu);
    k_scanF<<<dim3(kB * kP), 256, 0, stream>>>(Bu, Lbar);
    k_gemm2F<<<dim3(kL / 64, kH / 64, kB), 256, 0, stream>>>(
        (const float2*)C, (const float2*)Bu, input_sequence, D, out);
  }
}

// Round 4
// 279.068 us; speedup vs baseline: 1.1193x; 1.0431x over previous
//
#include <hip/hip_runtime.h>
#include <math.h>

// S5 SSM forward — R9: 2-phase pipelined MFMA GEMMs (T3 minimum recipe),
// 128x256 tile, BK=32, 8 waves of 64x64, 48 KiB LDS, 2-3 blocks/CU.
// R8 post-mortem: 8-phase schedule at BK=32 carries only 4 MFMA/wave per
// barrier-pair -> fixed per-phase cost dominates (MfmaUtil stuck ~19%).
// R9 uses ONE barrier + ONE vmcnt(0) per K-tile amortized over 16 MFMA/wave
// (m230: 2-phase 2562 = 682 TF refcheck'd), keeping R8's byte-identical
// st_16x32 swizzle staging (0 bank conflicts on HW) and epilogue.
// BSZ=4, L=4096, H=1024, P=512.

constexpr int kB = 4, kL = 4096, kH = 1024, kP = 512;
constexpr int kM = 1024, kK = 1024, kN = 4096;

typedef short bf16x8 __attribute__((ext_vector_type(8)));
typedef float f32x4 __attribute__((ext_vector_type(4)));

// ---- ws layout (bytes), MFMA path
constexpr size_t A1H_OFF = 0;                                    // 2 MiB
constexpr size_t A2H_OFF = A1H_OFF + (size_t)kM * kK * 2;        // 2 MiB
constexpr size_t LBAR_B  = A2H_OFF + (size_t)kM * kK * 2;        // 4 KiB
constexpr size_t BU_B    = (LBAR_B + 4096 + 255) & ~(size_t)255; // 64 MiB fp32
constexpr size_t TH_B    = BU_B + (size_t)kB * kM * kN * 4;      // 32 MiB bf16
constexpr size_t MID_BYTES = TH_B + (size_t)kB * kN * kK * 2;    // ~100 MiB

// ---- bf16 helpers
__device__ __forceinline__ unsigned short f2bf(float x) {
  unsigned int u = __float_as_uint(x);
  u += 0x7fffu + ((u >> 16) & 1u);
  return (unsigned short)(u >> 16);
}
__device__ __forceinline__ float bf2f(unsigned short h) {
  return __uint_as_float(((unsigned int)h) << 16);
}

__device__ __forceinline__ void gl2lds16(const void* g, void* l) {
  __builtin_amdgcn_global_load_lds(
      (const __attribute__((address_space(1))) void*)g,
      (__attribute__((address_space(3))) void*)l, 16, 0, 0);
}

// s_waitcnt with vmcnt=N, lgkmcnt/expcnt = don't-care
template <int N>
__device__ __forceinline__ void wait_vm() {
  __builtin_amdgcn_s_waitcnt((N & 15) | ((N >> 4) << 14) | (15 << 8) | (7 << 4));
}

// ---------------------------------------------------------------- prep (merged)
// blocks 0..511: prep1 (p = bid); blocks 512..1535: prep2 (h = bid-512)
__global__ __launch_bounds__(256) void k_prep12(
    const float* __restrict__ Lre, const float* __restrict__ Lim,
    const float* __restrict__ B, const float* __restrict__ log_step,
    const float* __restrict__ C, unsigned char* __restrict__ ws) {
  int bid = blockIdx.x;
  if (bid < kP) {
    int p = bid;
    float lr = Lre[p], li = Lim[p];
    float step = expf(log_step[p]);
    float er = expf(lr * step);
    float sb, cb;
    sincosf(li * step, &sb, &cb);
    float lbr = er * cb, lbi = er * sb;
    float nr = lbr - 1.0f, ni = lbi;
    float inv = 1.0f / (lr * lr + li * li);
    float sr = (nr * lr + ni * li) * inv;
    float si = (ni * lr - nr * li) * inv;

    if (threadIdx.x == 0) ((float2*)(ws + LBAR_B))[p] = make_float2(lbr, lbi);

    unsigned short* a1h = (unsigned short*)(ws + A1H_OFF);
    const float* Brow = B + (size_t)p * kH * 2;
    for (int h = threadIdx.x; h < kH; h += 256) {
      float br = Brow[2 * h], bi = Brow[2 * h + 1];
      a1h[(size_t)p * kK + h] = f2bf(sr * br - si * bi);
      a1h[(size_t)(kP + p) * kK + h] = f2bf(sr * bi + si * br);
    }
  } else {
    int h = bid - kP;
    unsigned short* a2h = (unsigned short*)(ws + A2H_OFF);
    for (int k = threadIdx.x; k < kK; k += 256) {
      float v = (k < kP) ? 2.f * C[((size_t)h * kP + k) * 2]
                         : -2.f * C[((size_t)h * kP + (k - kP)) * 2 + 1];
      a2h[(size_t)h * kK + k] = f2bf(v);
    }
  }
}

// ---------------------------------------------------------------- transpose (fp32 -> bf16T)
// in: fp32 [b][1024][4096] -> out: bf16 [b][4096][1024]   [replay-proven]
__global__ __launch_bounds__(256) void k_transpose(
    const float* __restrict__ in, unsigned short* __restrict__ oh) {
  __shared__ float t[64][65];
  int b = blockIdx.z;
  int r0 = blockIdx.y * 64;
  int c0 = blockIdx.x * 64;
  int tid = threadIdx.x;
  const float* src = in + ((size_t)b * 1024 + r0) * 4096 + c0;
  int cc = (tid & 15) * 4, rr = tid >> 4;
#pragma unroll
  for (int i = 0; i < 4; i++) {
    float4 v = *(const float4*)(src + (size_t)(rr + i * 16) * 4096 + cc);
    t[rr + i * 16][cc + 0] = v.x;
    t[rr + i * 16][cc + 1] = v.y;
    t[rr + i * 16][cc + 2] = v.z;
    t[rr + i * 16][cc + 3] = v.w;
  }
  __syncthreads();
  int oc = tid >> 2;
  int og = (tid & 3) * 2;
#pragma unroll
  for (int i = 0; i < 2; i++) {
    int g = og + i;
    unsigned short hv[8];
#pragma unroll
    for (int j = 0; j < 8; j++) hv[j] = f2bf(t[g * 8 + j][oc]);
    size_t ob = ((size_t)b * 4096 + c0 + oc) * 1024 + r0 + g * 8;
    *(uint4*)(oh + ob) = *(uint4*)hv;
  }
}

// ================================================================ 2-phase GEMM
// Tile 128(M) x 256(N), BK=32, 512 threads = 8 waves (2M x 4N), per-wave 64x64.
// LDS 48 KiB = 2 bufs x 24 KiB (A 8KB + B 16KB), 16x32-element subtiles
// (1024 B) with st_16x32 swizzle byte^=((byte>>9)&1)<<5, staged via
// global_load_lds with LINEAR dest + inverse-swizzled global src (rule #21;
// byte-identical decode to R8 which passed on HW with 0 bank conflicts).
// Per K-tile: STAGE next-buf (3 gl_lds) -> 8 ds_read -> lgkmcnt(0) ->
// setprio(1) 16 MFMA setprio(0) -> vmcnt(0) -> s_barrier.   [T3 min recipe]

__device__ __forceinline__ int stage_src_off32(int Dp) {
  int Ds = Dp ^ (((Dp >> 9) & 1) << 5);  // involution
  int s = Ds >> 10, d = Ds & 1023;       // subtile (row-block), within-subtile
  int row = (s << 4) + (d >> 6);         // 0..127
  int kk = (d & 63) >> 1;                // 0..31 (multiple of 8)
  return row * kK + kk;
}

#define BAR __builtin_amdgcn_s_barrier()
#define LGKM0                                           \
  do {                                                  \
    asm volatile("s_waitcnt lgkmcnt(0)" ::: "memory");  \
    __builtin_amdgcn_sched_barrier(0);                  \
  } while (0)

template <bool EPI>
__global__ __launch_bounds__(512, 4) void k_gemm2p(
    const unsigned short* __restrict__ Ah, const unsigned short* __restrict__ Bh,
    float* __restrict__ out, const float* __restrict__ u,
    const float* __restrict__ D) {
  __shared__ __align__(16) unsigned char lds[49152];
  constexpr int BUF = 24576;
  constexpr int NKT = kK / 32;  // 32 K-tiles

  int b = blockIdx.z;
  int m0 = blockIdx.y * 128, n0 = blockIdx.x * 256;
  int tid = threadIdx.x, w = tid >> 6;
  int q = (tid >> 4) & 3, r = tid & 15;
  int wm = (w >> 2) * 64, wn = (w & 3) * 64;
  int wmrb = (w >> 2) * 4, wnrb = (w & 3) * 4;
  int lane_off = (r * 64 + q * 16) ^ ((r & 8) << 2);  // st_16x32 read swizzle

  int d0 = tid << 4;
  int rowk = stage_src_off32(d0);  // same decode for A piece and each B half

  const unsigned short* pA = Ah + (size_t)m0 * kK;
  const unsigned short* pB = Bh + (size_t)b * kN * kK + (size_t)n0 * kK;

  f32x4 acc[4][4] = {};

  // one K-tile stage: A 8KB (rows 0-127) + B 16KB (two 8KB halves)
#define STG(KT, LB)                                                       \
  do {                                                                    \
    gl2lds16(pA + (KT) * 32 + rowk, lds + (LB) + d0);                     \
    gl2lds16(pB + (KT) * 32 + rowk, lds + (LB) + 8192 + d0);              \
    gl2lds16(pB + (size_t)128 * kK + (KT) * 32 + rowk,                    \
             lds + (LB) + 16384 + d0);                                    \
  } while (0)

  // one K-tile compute: 4 A-frags + 4 B-frags -> 16 MFMA into acc
#define COMPUTE(LB)                                                       \
  do {                                                                    \
    bf16x8 a[4], bb[4];                                                   \
    _Pragma("unroll")                                                     \
    for (int mi = 0; mi < 4; mi++)                                        \
      a[mi] = *(const bf16x8*)(lds + (LB) + ((wmrb + mi) << 10) + lane_off); \
    _Pragma("unroll")                                                     \
    for (int nj = 0; nj < 4; nj++)                                        \
      bb[nj] = *(const bf16x8*)(lds + (LB) + 8192 +                       \
                                ((wnrb + nj) << 10) + lane_off);          \
    LGKM0;                                                                \
    __builtin_amdgcn_s_setprio(1);                                        \
    _Pragma("unroll")                                                     \
    for (int mi = 0; mi < 4; mi++)                                        \
      _Pragma("unroll")                                                   \
      for (int nj = 0; nj < 4; nj++)                                      \
        acc[mi][nj] = __builtin_amdgcn_mfma_f32_16x16x32_bf16(            \
            a[mi], bb[nj], acc[mi][nj], 0, 0, 0);                         \
    __builtin_amdgcn_s_setprio(0);                                        \
  } while (0)

  // prologue: buf0 <- kt0
  STG(0, 0);
  wait_vm<0>();
  BAR;

  for (int it = 0; it < NKT / 2; ++it) {
    int kt = it * 2;
    // phase A: stage buf1 <- kt+1; compute buf0 (kt)
    if (kt + 1 < NKT) STG(kt + 1, BUF);
    COMPUTE(0);
    wait_vm<0>();  // kt+1 loads landed (had full MFMA phase to fly)
    BAR;           // also fences: all reads of buf0 done -> safe to restage
    // phase B: stage buf0 <- kt+2; compute buf1 (kt+1)
    if (kt + 2 < NKT) STG(kt + 2, 0);
    COMPUTE(BUF);
    wait_vm<0>();
    BAR;
  }
#undef STG
#undef COMPUTE

  // C/D layout: col = r, row = q*4 + reg   [R8-proven]
#pragma unroll
  for (int mi = 0; mi < 4; mi++) {
#pragma unroll
    for (int reg = 0; reg < 4; reg++) {
      int row = m0 + wm + mi * 16 + q * 4 + reg;
      float dv = EPI ? D[row] : 0.f;
#pragma unroll
      for (int ni = 0; ni < 4; ni++) {
        int col = n0 + wn + ni * 16 + r;
        size_t o = ((size_t)b * kM + row) * (size_t)kN + col;
        float v = acc[mi][ni][reg];
        if (EPI) {
          float y = v + dv * u[o];
          v = 0.5f * y * (1.f + erff(y * 0.70710678118654752f));
        }
        out[o] = v;
      }
    }
  }
}

// ---------------------------------------------------------------- scan (fp32 planar, in-place)
// [replay-proven]
__global__ __launch_bounds__(256) void k_scan(float* __restrict__ bu,
                                              const float2* __restrict__ lbar) {
  int p = blockIdx.x & (kP - 1);
  int b = blockIdx.x >> 9;
  int tid = threadIdx.x, lane = tid & 63, w = tid >> 6;
  float2 lam = lbar[p];
  float* sre = bu + ((size_t)b * kM + p) * (size_t)kN;
  float* sim = sre + (size_t)kP * kN;

  float vr[16], vi[16];
  {
    const float4* pr = (const float4*)(sre + tid * 16);
    const float4* pi = (const float4*)(sim + tid * 16);
#pragma unroll
    for (int i = 0; i < 4; i++) {
      float4 a = pr[i], c = pi[i];
      vr[4 * i] = a.x; vr[4 * i + 1] = a.y; vr[4 * i + 2] = a.z; vr[4 * i + 3] = a.w;
      vi[4 * i] = c.x; vi[4 * i + 1] = c.y; vi[4 * i + 2] = c.z; vi[4 * i + 3] = c.w;
    }
  }

  float xr = 0.f, xi = 0.f;
#pragma unroll
  for (int i = 0; i < 16; i++) {
    float nr2 = fmaf(lam.x, xr, fmaf(-lam.y, xi, vr[i]));
    float ni2 = fmaf(lam.x, xi, fmaf(lam.y, xr, vi[i]));
    xr = nr2; xi = ni2;
  }

  float Ar = lam.x, Ai = lam.y;
#pragma unroll
  for (int s = 0; s < 4; s++) {
    float tr = Ar * Ar - Ai * Ai, ti = 2.f * Ar * Ai;
    Ar = tr; Ai = ti;
  }
  float br = xr, bi = xi;

  for (int off = 1; off < 64; off <<= 1) {
    float pAr = __shfl_up(Ar, off), pAi = __shfl_up(Ai, off);
    float pbr = __shfl_up(br, off), pbi = __shfl_up(bi, off);
    if (lane >= off) {
      float nAr = Ar * pAr - Ai * pAi;
      float nAi = Ar * pAi + Ai * pAr;
      float nbr = Ar * pbr - Ai * pbi + br;
      float nbi = Ar * pbi + Ai * pbr + bi;
      Ar = nAr; Ai = nAi; br = nbr; bi = nbi;
    }
  }

  __shared__ float4 wtot[4];
  if (lane == 63) wtot[w] = make_float4(Ar, Ai, br, bi);
  __syncthreads();

  float eAr = __shfl_up(Ar, 1), eAi = __shfl_up(Ai, 1);
  float ebr = __shfl_up(br, 1), ebi = __shfl_up(bi, 1);
  if (lane == 0) { eAr = 1.f; eAi = 0.f; ebr = 0.f; ebi = 0.f; }

  float pAr = 1.f, pAi = 0.f, pbr = 0.f, pbi = 0.f;
  for (int j = 0; j < w; j++) {
    float4 t = wtot[j];
    float nAr = t.x * pAr - t.y * pAi;
    float nAi = t.x * pAi + t.y * pAr;
    float nbr = t.x * pbr - t.y * pbi + t.z;
    float nbi = t.x * pbi + t.y * pbr + t.w;
    pAr = nAr; pAi = nAi; pbr = nbr; pbi = nbi;
  }

  float initr = eAr * pbr - eAi * pbi + ebr;
  float initi = eAr * pbi + eAi * pbr + ebi;

  xr = initr; xi = initi;
  float4* qr = (float4*)(sre + tid * 16);
  float4* qi = (float4*)(sim + tid * 16);
#pragma unroll
  for (int i = 0; i < 4; i++) {
    float rr[4], ii[4];
#pragma unroll
    for (int j = 0; j < 4; j++) {
      float nr2 = fmaf(lam.x, xr, fmaf(-lam.y, xi, vr[4 * i + j]));
      float ni2 = fmaf(lam.x, xi, fmaf(lam.y, xr, vi[4 * i + j]));
      xr = nr2; xi = ni2; rr[j] = nr2; ii[j] = ni2;
    }
    qr[i] = make_float4(rr[0], rr[1], rr[2], rr[3]);
    qi[i] = make_float4(ii[0], ii[1], ii[2], ii[3]);
  }
}

// ================================================================ fp32 fallback
constexpr size_t OBBAR = 0;
constexpr size_t OLBAR = (size_t)kP * kH;
constexpr size_t OBU = OLBAR + 1024;

__global__ __launch_bounds__(256) void k_precomputeF(
    const float* __restrict__ Lre, const float* __restrict__ Lim,
    const float* __restrict__ B, const float* __restrict__ log_step,
    float2* __restrict__ ws) {
  int p = blockIdx.x;
  float lr = Lre[p], li = Lim[p];
  float step = expf(log_step[p]);
  float er = expf(lr * step);
  float sb, cb;
  sincosf(li * step, &sb, &cb);
  float lbr = er * cb, lbi = er * sb;
  float nr = lbr - 1.0f, ni = lbi;
  float inv = 1.0f / (lr * lr + li * li);
  float sr = (nr * lr + ni * li) * inv;
  float si = (ni * lr - nr * li) * inv;
  if (threadIdx.x == 0) ws[OLBAR + p] = make_float2(lbr, lbi);
  float2* Bbar = ws + OBBAR;
  const float* Brow = B + (size_t)p * kH * 2;
  for (int h = threadIdx.x; h < kH; h += 256) {
    float br = Brow[2 * h], bi = Brow[2 * h + 1];
    Bbar[(size_t)p * kH + h] = make_float2(sr * br - si * bi, sr * bi + si * br);
  }
}

__global__ __launch_bounds__(256) void k_gemm1F(
    const float2* __restrict__ ws_bbar, const float* __restrict__ u,
    float2* __restrict__ Bu) {
  __shared__ float2 As[16][64];
  __shared__ float Bs[16][64];
  int b = blockIdx.z, m0 = blockIdx.y * 64, n0 = blockIdx.x * 64;
  int tid = threadIdx.x, tn = tid & 15, tm = tid >> 4;
  const float* uB = u + (size_t)b * kH * kL;
  float2 acc[4][4];
#pragma unroll
  for (int i = 0; i < 4; i++)
#pragma unroll
    for (int j = 0; j < 4; j++) acc[i][j] = make_float2(0.f, 0.f);
  int ar = tid >> 2, ac = (tid & 3) * 4, bk = tid >> 4, bc = (tid & 15) * 4;
  for (int k0 = 0; k0 < kH; k0 += 16) {
    const float4* src = (const float4*)(ws_bbar + (size_t)(m0 + ar) * kH + k0 + ac);
    float4 v01 = src[0], v23 = src[1];
    As[ac + 0][ar] = make_float2(v01.x, v01.y);
    As[ac + 1][ar] = make_float2(v01.z, v01.w);
    As[ac + 2][ar] = make_float2(v23.x, v23.y);
    As[ac + 3][ar] = make_float2(v23.z, v23.w);
    float4 v = *(const float4*)(uB + (size_t)(k0 + bk) * kL + n0 + bc);
    *(float4*)&Bs[bk][bc] = v;
    __syncthreads();
#pragma unroll
    for (int kk = 0; kk < 16; ++kk) {
      const float4* arow = (const float4*)&As[kk][0];
      float4 a01 = arow[tm * 2 + 0], a23 = arow[tm * 2 + 1];
      float2 a[4] = {make_float2(a01.x, a01.y), make_float2(a01.z, a01.w),
                     make_float2(a23.x, a23.y), make_float2(a23.z, a23.w)};
      float4 bv = ((const float4*)&Bs[kk][0])[tn];
      float bbv[4] = {bv.x, bv.y, bv.z, bv.w};
#pragma unroll
      for (int mi = 0; mi < 4; mi++)
#pragma unroll
        for (int ni = 0; ni < 4; ni++) {
          acc[mi][ni].x = fmaf(a[mi].x, bbv[ni], acc[mi][ni].x);
          acc[mi][ni].y = fmaf(a[mi].y, bbv[ni], acc[mi][ni].y);
        }
    }
    __syncthreads();
  }
  float2* BuB = Bu + (size_t)b * kP * kL;
#pragma unroll
  for (int mi = 0; mi < 4; mi++) {
    int row = m0 + tm * 4 + mi;
    float2* dst = BuB + (size_t)row * kL + n0 + tn * 4;
    ((float4*)dst)[0] = make_float4(acc[mi][0].x, acc[mi][0].y, acc[mi][1].x, acc[mi][1].y);
    ((float4*)dst)[1] = make_float4(acc[mi][2].x, acc[mi][2].y, acc[mi][3].x, acc[mi][3].y);
  }
}

__global__ __launch_bounds__(256) void k_scanF(float2* __restrict__ Bu,
                                               const float2* __restrict__ Lbar) {
  int p = blockIdx.x & (kP - 1);
  int b = blockIdx.x >> 9;
  int tid = threadIdx.x, lane = tid & 63, w = tid >> 6;
  float2 lam = Lbar[p];
  float2* seq = Bu + ((size_t)b * kP + p) * kL;
  float2 v[16];
  const float4* src = (const float4*)(seq + tid * 16);
#pragma unroll
  for (int i = 0; i < 8; i++) {
    float4 t = src[i];
    v[2 * i] = make_float2(t.x, t.y);
    v[2 * i + 1] = make_float2(t.z, t.w);
  }
  float xr = 0.f, xi = 0.f;
#pragma unroll
  for (int i = 0; i < 16; i++) {
    float nr2 = fmaf(lam.x, xr, fmaf(-lam.y, xi, v[i].x));
    float ni2 = fmaf(lam.x, xi, fmaf(lam.y, xr, v[i].y));
    xr = nr2; xi = ni2;
  }
  float Ar = lam.x, Ai = lam.y;
#pragma unroll
  for (int s = 0; s < 4; s++) {
    float tr = Ar * Ar - Ai * Ai, ti = 2.f * Ar * Ai;
    Ar = tr; Ai = ti;
  }
  float br = xr, bi = xi;
  for (int off = 1; off < 64; off <<= 1) {
    float pAr = __shfl_up(Ar, off), pAi = __shfl_up(Ai, off);
    float pbr = __shfl_up(br, off), pbi = __shfl_up(bi, off);
    if (lane >= off) {
      float nAr = Ar * pAr - Ai * pAi, nAi = Ar * pAi + Ai * pAr;
      float nbr = Ar * pbr - Ai * pbi + br, nbi = Ar * pbi + Ai * pbr + bi;
      Ar = nAr; Ai = nAi; br = nbr; bi = nbi;
    }
  }
  __shared__ float4 wtot[4];
  if (lane == 63) wtot[w] = make_float4(Ar, Ai, br, bi);
  __syncthreads();
  float eAr = __shfl_up(Ar, 1), eAi = __shfl_up(Ai, 1);
  float ebr = __shfl_up(br, 1), ebi = __shfl_up(bi, 1);
  if (lane == 0) { eAr = 1.f; eAi = 0.f; ebr = 0.f; ebi = 0.f; }
  float pAr = 1.f, pAi = 0.f, pbr = 0.f, pbi = 0.f;
  for (int j = 0; j < w; j++) {
    float4 t = wtot[j];
    float nAr = t.x * pAr - t.y * pAi, nAi = t.x * pAi + t.y * pAr;
    float nbr = t.x * pbr - t.y * pbi + t.z, nbi = t.x * pbi + t.y * pbr + t.w;
    pAr = nAr; pAi = nAi; pbr = nbr; pbi = nbi;
  }
  float initr = eAr * pbr - eAi * pbi + ebr;
  float initi = eAr * pbi + eAi * pbr + ebi;
  xr = initr; xi = initi;
  float4* dst = (float4*)(seq + tid * 16);
#pragma unroll
  for (int i = 0; i < 8; i++) {
    float nr0 = fmaf(lam.x, xr, fmaf(-lam.y, xi, v[2 * i].x));
    float ni0 = fmaf(lam.x, xi, fmaf(lam.y, xr, v[2 * i].y));
    float nr1 = fmaf(lam.x, nr0, fmaf(-lam.y, ni0, v[2 * i + 1].x));
    float ni1 = fmaf(lam.x, ni0, fmaf(lam.y, nr0, v[2 * i + 1].y));
    dst[i] = make_float4(nr0, ni0, nr1, ni1);
    xr = nr1; xi = ni1;
  }
}

__global__ __launch_bounds__(256) void k_gemm2F(
    const float2* __restrict__ C, const float2* __restrict__ X,
    const float* __restrict__ u, const float* __restrict__ D,
    float* __restrict__ out) {
  __shared__ float2 As[16][64];
  __shared__ float2 Bs[16][64];
  int b = blockIdx.z, m0 = blockIdx.y * 64, n0 = blockIdx.x * 64;
  int tid = threadIdx.x, tn = tid & 15, tm = tid >> 4;
  const float2* Xb = X + (size_t)b * kP * kL;
  float acc[4][4];
#pragma unroll
  for (int i = 0; i < 4; i++)
#pragma unroll
    for (int j = 0; j < 4; j++) acc[i][j] = 0.f;
  int ar = tid >> 2, ac = (tid & 3) * 4, bk = tid >> 4, bc = (tid & 15) * 4;
  for (int k0 = 0; k0 < kP; k0 += 16) {
    const float4* src = (const float4*)(C + (size_t)(m0 + ar) * kP + k0 + ac);
    float4 v01 = src[0], v23 = src[1];
    As[ac + 0][ar] = make_float2(v01.x, v01.y);
    As[ac + 1][ar] = make_float2(v01.z, v01.w);
    As[ac + 2][ar] = make_float2(v23.x, v23.y);
    As[ac + 3][ar] = make_float2(v23.z, v23.w);
    const float4* srcb = (const float4*)(Xb + (size_t)(k0 + bk) * kL + n0 + bc);
    ((float4*)&Bs[bk][bc])[0] = srcb[0];
    ((float4*)&Bs[bk][bc])[1] = srcb[1];
    __syncthreads();
#pragma unroll
    for (int kk = 0; kk < 16; ++kk) {
      const float4* arow = (const float4*)&As[kk][0];
      float4 a01 = arow[tm * 2 + 0], a23 = arow[tm * 2 + 1];
      float2 a[4] = {make_float2(a01.x, a01.y), make_float2(a01.z, a01.w),
                     make_float2(a23.x, a23.y), make_float2(a23.z, a23.w)};
      const float4* brow = (const float4*)&Bs[kk][0];
      float4 b01 = brow[tn * 2 + 0], b23 = brow[tn * 2 + 1];
      float2 bbv[4] = {make_float2(b01.x, b01.y), make_float2(b01.z, b01.w),
                       make_float2(b23.x, b23.y), make_float2(b23.z, b23.w)};
#pragma unroll
      for (int mi = 0; mi < 4; mi++)
#pragma unroll
        for (int ni = 0; ni < 4; ni++) {
          acc[mi][ni] = fmaf(a[mi].x, bbv[ni].x, acc[mi][ni]);
          acc[mi][ni] = fmaf(-a[mi].y, bbv[ni].y, acc[mi][ni]);
        }
    }
    __syncthreads();
  }
#pragma unroll
  for (int mi = 0; mi < 4; mi++) {
    int h = m0 + tm * 4 + mi;
    float d = D[h];
    const float* urow = u + ((size_t)b * kH + h) * kL + n0 + tn * 4;
    float4 uv = *(const float4*)urow;
    float uu[4] = {uv.x, uv.y, uv.z, uv.w};
    float res[4];
#pragma unroll
    for (int ni = 0; ni < 4; ni++) {
      float y = 2.f * acc[mi][ni] + d * uu[ni];
      res[ni] = 0.5f * y * (1.f + erff(y * 0.70710678118654752f));
    }
    float* orow = out + ((size_t)b * kH + h) * kL + n0 + tn * 4;
    *(float4*)orow = make_float4(res[0], res[1], res[2], res[3]);
  }
}

// ---------------------------------------------------------------- launch
extern "C" void kernel_launch(void* const* d_in, const int* in_sizes, int n_in,
                              void* d_out, int out_size, void* d_ws, size_t ws_size,
                              hipStream_t stream) {
  const float* input_sequence = (const float*)d_in[0];
  const float* Lambda_re = (const float*)d_in[2];
  const float* Lambda_im = (const float*)d_in[3];
  const float* B = (const float*)d_in[4];
  const float* C = (const float*)d_in[5];
  const float* D = (const float*)d_in[6];
  const float* log_step = (const float*)d_in[7];
  float* out = (float*)d_out;

  if (ws_size >= MID_BYTES) {
    unsigned char* ws = (unsigned char*)d_ws;
    unsigned short* a1h = (unsigned short*)(ws + A1H_OFF);
    unsigned short* a2h = (unsigned short*)(ws + A2H_OFF);
    float2* lbar = (float2*)(ws + LBAR_B);
    float* bu = (float*)(ws + BU_B);
    unsigned short* th = (unsigned short*)(ws + TH_B);

    k_prep12<<<dim3(kP + kH), 256, 0, stream>>>(Lambda_re, Lambda_im, B,
                                                log_step, C, ws);

    dim3 tgrid(kL / 64, 1024 / 64, kB);
    dim3 ggrid(kN / 256, kM / 128, kB);  // 16 x 8 x 4 = 512 blocks

    k_transpose<<<tgrid, 256, 0, stream>>>(input_sequence, th);
    k_gemm2p<false><<<ggrid, 512, 0, stream>>>(a1h, th, bu, nullptr, nullptr);
    k_scan<<<dim3(kB * kP), 256, 0, stream>>>(bu, lbar);
    k_transpose<<<tgrid, 256, 0, stream>>>(bu, th);
    k_gemm2p<true><<<ggrid, 512, 0, stream>>>(a2h, th, out, input_sequence, D);
  } else {
    // fp32 fallback (round-1 path)
    float2* ws = (float2*)d_ws;
    float2* Bbar = ws + OBBAR;
    float2* Lbar = ws + OLBAR;
    float2* Bu = ws + OBU;
    k_precomputeF<<<dim3(kP), 256, 0, stream>>>(Lambda_re, Lambda_im, B, log_step, ws);
    k_gemm1F<<<dim3(kL / 64, kP / 64, kB), 256, 0, stream>>>(Bbar, input_sequence, Bu);
    k_scanF<<<dim3(kB * kP), 256, 0, stream>>>(Bu, Lbar);
    k_gemm2F<<<dim3(kL / 64, kH / 64, kB), 256, 0, stream>>>(
        (const float2*)C, (const float2*)Bu, input_sequence, D, out);
  }
}